// Round 12
// baseline (530.065 us; speedup 1.0000x reference)
//
#include <hip/hip_runtime.h>
#include <hip/hip_bf16.h>
#include <math.h>

// ---------------------------------------------------------------------------
// Round 12: revert to r8-proven structure (441us, stable 0.03125); add
// k_mgemm2 (128x128 tile, same sync skeleton) for w1 and qkv cols 0..511.
// r9-r11's k_qkv/k_mlp had a timing-dependent corruption (post-timing output
// divergence) -- abandoned.
//   k_wprep x6:  weights fp32 [K][N] -> bf16 transposed [N][K]
//   k_tin:       x[B,C,H,W] -> xt[u,192] bf16 (window-major token order)
//   k_mgemm2/k_mgemm: qkv[u,576] = xt @ [wq|wk|wv]  (128-wide + 64-wide rem)
//   k_attn2:     MFMA window attention; y overwrites v-slots of qkv
//   k_gemmln:    x1 = LN(y @ wo + xt)*g1+b1   (in-place over xt)
//   2x { k_mgemm2 w1+GELU ; k_gemmln w2+LN2 } (x2 in-place over x1)
//   k_tout:      out = transpose(x2) fp32
// ---------------------------------------------------------------------------

#define DEVI __device__ __forceinline__

static constexpr int CH   = 192;
static constexpr int NTOK = 32 * 64 * 64;   // 131072
static constexpr int MLPD = 768;

typedef short bf16x8 __attribute__((ext_vector_type(8)));
typedef float f32x4  __attribute__((ext_vector_type(4)));

DEVI float bf2f(unsigned short u) { return __uint_as_float(((unsigned)u) << 16); }
DEVI unsigned short f2bf(float f) {
    __hip_bfloat16 h = __float2bfloat16(f);
    return *reinterpret_cast<unsigned short*>(&h);
}

DEVI void gload_lds16(const void* g, void* l) {
    __builtin_amdgcn_global_load_lds(
        (const __attribute__((address_space(1))) void*)g,
        (__attribute__((address_space(3))) void*)l, 16, 0, 0);
}

// ---------------- weight prep: W[K][N] fp32 -> Wt[N][K] bf16 ----------------
__global__ __launch_bounds__(256) void k_wprep(const float* __restrict__ W,
                                               __hip_bfloat16* __restrict__ Wt,
                                               int K, int N) {
    int idx = blockIdx.x * 256 + threadIdx.x;
    if (idx >= K * N) return;
    int n = idx / K, k = idx - n * K;
    Wt[idx] = __float2bfloat16(W[(size_t)k * N + n]);
}

// ---------------- transpose in: x[b,c,h,w] -> xt[u,c] bf16 ------------------
__global__ __launch_bounds__(256) void k_tin(const float* __restrict__ x,
                                             __hip_bfloat16* __restrict__ xt) {
    __shared__ float lds[CH * 65];
    int bh = blockIdx.x;              // b*64 + h
    int b = bh >> 6, h = bh & 63;
    const float* xp = x + ((size_t)b * CH) * 4096 + (size_t)h * 64;
    int tid = threadIdx.x;
    int w = tid & 63;
    #pragma unroll
    for (int it = 0; it < CH / 4; ++it) {
        int c = it * 4 + (tid >> 6);
        lds[c * 65 + w] = xp[(size_t)c * 4096 + w];
    }
    __syncthreads();
    int m1 = h >> 4, h0 = h & 15;
    int ubase = (b << 12) | (h0 << 8) | (m1 << 2);
    #pragma unroll
    for (int it = 0; it < 48; ++it) {
        int idx = it * 256 + tid;
        int tok = idx / CH;
        int c = idx - tok * CH;
        int u = ubase | ((tok & 15) << 4) | (tok >> 4);
        xt[(size_t)u * CH + c] = __float2bfloat16(lds[c * 65 + tok]);
    }
}

// ---------------- MFMA GEMM, 128x64 tile, dbuf prefetch (r8-proven) ---------
// C[r, n0..n0+63] = act(A[rows,K] @ Bt[N,K]^T + bias), n0 = nbase + bx*64.
template<int K, bool GELU, bool BIAS>
__global__ __launch_bounds__(256) void k_mgemm(const __hip_bfloat16* __restrict__ A,
                                               const __hip_bfloat16* __restrict__ Bt,
                                               const float* __restrict__ bias,
                                               __hip_bfloat16* __restrict__ Cm,
                                               const int nbase,
                                               const int LDA, const int LDC) {
    __shared__ __align__(16) char smem[49152];   // 2 x (As 16KB + Bs 8KB)
    const int tid = threadIdx.x;
    const int l  = tid & 63;
    const int w  = tid >> 6;
    const int wr = w >> 1, wc = w & 1;
    const int r0 = blockIdx.y * 128;
    const int n0 = nbase + blockIdx.x * 64;
    constexpr int NT = K / 64;

    f32x4 acc[4][2] = {};

    auto stage = [&](int bi, int kt) {
        #pragma unroll
        for (int it = 0; it < 4; ++it) {
            int c = it * 4 + w, s = c * 64 + l, row = s >> 3;
            int eb = ((s & 7) << 4) ^ ((row & 7) << 4);
            gload_lds16(A + (size_t)(r0 + row) * LDA + kt * 64 + (eb >> 1),
                        smem + bi * 24576 + c * 1024);
        }
        #pragma unroll
        for (int it = 0; it < 2; ++it) {
            int c = it * 4 + w, s = c * 64 + l, row = s >> 3;
            int eb = ((s & 7) << 4) ^ ((row & 7) << 4);
            gload_lds16(Bt + (size_t)(n0 + row) * K + kt * 64 + (eb >> 1),
                        smem + bi * 24576 + 16384 + c * 1024);
        }
    };

    stage(0, 0);
    __syncthreads();
    #pragma unroll
    for (int kt = 0; kt < NT; ++kt) {
        const int cur = kt & 1;
        if (kt + 1 < NT) stage(cur ^ 1, kt + 1);   // prefetch BEFORE compute
        char* As = smem + cur * 24576;
        char* Bs = smem + cur * 24576 + 16384;
        #pragma unroll
        for (int ks = 0; ks < 2; ++ks) {
            int kb = ks * 64 + ((l >> 4) << 4);
            bf16x8 af[4], bfr[2];
            #pragma unroll
            for (int m = 0; m < 4; ++m) {
                int row = wr * 64 + m * 16 + (l & 15);
                af[m] = *(const bf16x8*)(As + row * 128 + (kb ^ ((row & 7) << 4)));
            }
            #pragma unroll
            for (int n = 0; n < 2; ++n) {
                int row = wc * 32 + n * 16 + (l & 15);
                bfr[n] = *(const bf16x8*)(Bs + row * 128 + (kb ^ ((row & 7) << 4)));
            }
            #pragma unroll
            for (int m = 0; m < 4; ++m)
                #pragma unroll
                for (int n = 0; n < 2; ++n)
                    acc[m][n] = __builtin_amdgcn_mfma_f32_16x16x32_bf16(
                        af[m], bfr[n], acc[m][n], 0, 0, 0);
        }
        __syncthreads();
    }

    const int rl = (l >> 4) * 4;
    const int cl = l & 15;
    #pragma unroll
    for (int n = 0; n < 2; ++n) {
        int col = n0 + wc * 32 + n * 16 + cl;
        float bv = 0.f;
        if constexpr (BIAS) bv = bias[col];
        #pragma unroll
        for (int m = 0; m < 4; ++m) {
            #pragma unroll
            for (int j = 0; j < 4; ++j) {
                size_t row = (size_t)r0 + wr * 64 + m * 16 + rl + j;
                float v = acc[m][n][j] + bv;
                if constexpr (GELU) v = 0.5f * v * (1.0f + erff(v * 0.70710678118654752f));
                Cm[row * LDC + col] = __float2bfloat16(v);
            }
        }
    }
}

// ---------------- MFMA GEMM, 128x128 tile, dbuf prefetch --------------------
// Same skeleton as k_mgemm; wave tile 64x64 (acc 4x4). N must divide by 128.
template<int K, bool GELU, bool BIAS>
__global__ __launch_bounds__(256) void k_mgemm2(const __hip_bfloat16* __restrict__ A,
                                                const __hip_bfloat16* __restrict__ Bt,
                                                const float* __restrict__ bias,
                                                __hip_bfloat16* __restrict__ Cm,
                                                const int nbase,
                                                const int LDA, const int LDC) {
    __shared__ __align__(16) char smem[65536];   // 2 x (As 16KB + Bs 16KB)
    const int tid = threadIdx.x;
    const int l  = tid & 63;
    const int w  = tid >> 6;
    const int wr = w >> 1, wc = w & 1;
    const int r0 = blockIdx.y * 128;
    const int n0 = nbase + blockIdx.x * 128;
    constexpr int NT = K / 64;

    f32x4 acc[4][4] = {};

    auto stage = [&](int bi, int kt) {
        #pragma unroll
        for (int it = 0; it < 4; ++it) {
            int c = it * 4 + w, s = c * 64 + l, row = s >> 3;
            int eb = ((s & 7) << 4) ^ ((row & 7) << 4);
            gload_lds16(A + (size_t)(r0 + row) * LDA + kt * 64 + (eb >> 1),
                        smem + bi * 32768 + c * 1024);
        }
        #pragma unroll
        for (int it = 0; it < 4; ++it) {
            int c = it * 4 + w, s = c * 64 + l, row = s >> 3;
            int eb = ((s & 7) << 4) ^ ((row & 7) << 4);
            gload_lds16(Bt + (size_t)(n0 + row) * K + kt * 64 + (eb >> 1),
                        smem + bi * 32768 + 16384 + c * 1024);
        }
    };

    stage(0, 0);
    __syncthreads();
    #pragma unroll
    for (int kt = 0; kt < NT; ++kt) {
        const int cur = kt & 1;
        if (kt + 1 < NT) stage(cur ^ 1, kt + 1);
        char* As = smem + cur * 32768;
        char* Bs = smem + cur * 32768 + 16384;
        #pragma unroll
        for (int ks = 0; ks < 2; ++ks) {
            int kb = ks * 64 + ((l >> 4) << 4);
            bf16x8 af[4], bfr[4];
            #pragma unroll
            for (int m = 0; m < 4; ++m) {
                int row = wr * 64 + m * 16 + (l & 15);
                af[m] = *(const bf16x8*)(As + row * 128 + (kb ^ ((row & 7) << 4)));
            }
            #pragma unroll
            for (int n = 0; n < 4; ++n) {
                int row = wc * 64 + n * 16 + (l & 15);
                bfr[n] = *(const bf16x8*)(Bs + row * 128 + (kb ^ ((row & 7) << 4)));
            }
            #pragma unroll
            for (int m = 0; m < 4; ++m)
                #pragma unroll
                for (int n = 0; n < 4; ++n)
                    acc[m][n] = __builtin_amdgcn_mfma_f32_16x16x32_bf16(
                        af[m], bfr[n], acc[m][n], 0, 0, 0);
        }
        __syncthreads();
    }

    const int rl = (l >> 4) * 4;
    const int cl = l & 15;
    #pragma unroll
    for (int n = 0; n < 4; ++n) {
        int col = n0 + wc * 64 + n * 16 + cl;
        float bv = 0.f;
        if constexpr (BIAS) bv = bias[col];
        #pragma unroll
        for (int m = 0; m < 4; ++m) {
            #pragma unroll
            for (int j = 0; j < 4; ++j) {
                size_t row = (size_t)r0 + wr * 64 + m * 16 + rl + j;
                float v = acc[m][n][j] + bv;
                if constexpr (GELU) v = 0.5f * v * (1.0f + erff(v * 0.70710678118654752f));
                Cm[row * LDC + col] = __float2bfloat16(v);
            }
        }
    }
}

// ---------------- full-row GEMM + residual + LayerNorm, dbuf prefetch -------
// Out[r,0..191] = LN(A[rows,K] @ Bt[192,K]^T + bias + Res[r,:]) * g + be.
template<int K, bool BIAS>
__global__ __launch_bounds__(256) void k_gemmln(const __hip_bfloat16* __restrict__ A,
                                                const __hip_bfloat16* __restrict__ Bt,
                                                const float* __restrict__ bias,
                                                const __hip_bfloat16* Res,
                                                const float* __restrict__ g,
                                                const float* __restrict__ be,
                                                __hip_bfloat16* Out,
                                                const int LDA) {
    __shared__ __align__(16) char smem[65536];   // 2 x (As 8KB + Bs 24KB)
    const int tid = threadIdx.x;
    const int l  = tid & 63;
    const int w  = tid >> 6;
    const int cl = l & 15;
    const int kq = l >> 4;
    const int r0 = blockIdx.x * 64;
    constexpr int NT = K / 64;

    f32x4 acc[12] = {};

    auto stage = [&](int bi, int kt) {
        #pragma unroll
        for (int it = 0; it < 2; ++it) {
            int c = it * 4 + w, s = c * 64 + l, row = s >> 3;
            int eb = ((s & 7) << 4) ^ ((row & 7) << 4);
            gload_lds16(A + (size_t)(r0 + row) * LDA + kt * 64 + (eb >> 1),
                        smem + bi * 32768 + c * 1024);
        }
        #pragma unroll
        for (int it = 0; it < 6; ++it) {
            int c = it * 4 + w, s = c * 64 + l, row = s >> 3;
            int eb = ((s & 7) << 4) ^ ((row & 7) << 4);
            gload_lds16(Bt + (size_t)row * K + kt * 64 + (eb >> 1),
                        smem + bi * 32768 + 8192 + c * 1024);
        }
    };

    stage(0, 0);
    __syncthreads();
    #pragma unroll
    for (int kt = 0; kt < NT; ++kt) {
        const int cur = kt & 1;
        if (kt + 1 < NT) stage(cur ^ 1, kt + 1);
        char* As = smem + cur * 32768;
        char* Bs = smem + cur * 32768 + 8192;
        #pragma unroll
        for (int ks = 0; ks < 2; ++ks) {
            int kb = ks * 64 + (kq << 4);
            int arow = w * 16 + cl;
            bf16x8 af = *(const bf16x8*)(As + arow * 128 + (kb ^ ((arow & 7) << 4)));
            #pragma unroll
            for (int n = 0; n < 12; ++n) {
                int row = n * 16 + cl;
                bf16x8 b = *(const bf16x8*)(Bs + row * 128 + (kb ^ ((row & 7) << 4)));
                acc[n] = __builtin_amdgcn_mfma_f32_16x16x32_bf16(af, b, acc[n], 0, 0, 0);
            }
        }
        __syncthreads();
    }

    float gv[12], bev[12], bv[12];
    #pragma unroll
    for (int n = 0; n < 12; ++n) {
        int col = n * 16 + cl;
        gv[n]  = g[col];
        bev[n] = be[col];
        bv[n]  = BIAS ? bias[col] : 0.f;
    }
    #pragma unroll
    for (int r = 0; r < 4; ++r) {
        size_t row = (size_t)r0 + w * 16 + kq * 4 + r;
        float v[12];
        float sum = 0.f;
        #pragma unroll
        for (int n = 0; n < 12; ++n) {
            int col = n * 16 + cl;
            v[n] = acc[n][r] + bv[n] +
                   bf2f(*reinterpret_cast<const unsigned short*>(Res + row * 192 + col));
            sum += v[n];
        }
        sum += __shfl_xor(sum, 1);
        sum += __shfl_xor(sum, 2);
        sum += __shfl_xor(sum, 4);
        sum += __shfl_xor(sum, 8);
        float mean = sum * (1.0f / 192.0f);
        float ss = 0.f;
        #pragma unroll
        for (int n = 0; n < 12; ++n) { v[n] -= mean; ss += v[n] * v[n]; }
        ss += __shfl_xor(ss, 1);
        ss += __shfl_xor(ss, 2);
        ss += __shfl_xor(ss, 4);
        ss += __shfl_xor(ss, 8);
        float rs = rsqrtf(ss * (1.0f / 192.0f) + 1e-5f);
        #pragma unroll
        for (int n = 0; n < 12; ++n) {
            int col = n * 16 + cl;
            *reinterpret_cast<unsigned short*>(Out + row * 192 + col) =
                f2bf(v[n] * rs * gv[n] + bev[n]);
        }
    }
}

// ---------------- MFMA window attention (r8-proven) -------------------------
__global__ __launch_bounds__(256) void k_attn2(__hip_bfloat16* qkv) {
    __shared__ __align__(16) char lds[4 * 13568];
    const int tid = threadIdx.x;
    const int l = tid & 63;
    const int w = tid >> 6;
    const int win = blockIdx.x * 4 + w;
    char* vt = lds + w * 13568;
    char* pb = vt + 12288;

    #pragma unroll
    for (int rr = 0; rr < 3; ++rr) {
        char* zp = vt + (l * 3 + rr) * 64 + 32;
        *(uint4*)zp        = make_uint4(0u, 0u, 0u, 0u);
        *(uint4*)(zp + 16) = make_uint4(0u, 0u, 0u, 0u);
    }
    {
        int r = l >> 2, o = (l & 3) * 8;
        *(uint2*)(pb + r * 80 + 32 + o) = make_uint2(0u, 0u);
    }

    const __hip_bfloat16* base = qkv + (size_t)win * 16 * 576;

    uint4 vr[6];
    #pragma unroll
    for (int it = 0; it < 6; ++it) {
        int flat = it * 64 + l;
        int row = flat / 24, seg = flat - row * 24;
        vr[it] = *(const uint4*)(base + (size_t)row * 576 + 384 + seg * 8);
    }
    bf16x8 qf[6], kf[6];
    #pragma unroll
    for (int h = 0; h < 6; ++h) {
        const __hip_bfloat16* rp = base + (size_t)(l & 15) * 576;
        int off = h * 32 + (l >> 4) * 8;
        qf[h] = *(const bf16x8*)(rp + off);
        kf[h] = *(const bf16x8*)(rp + 192 + off);
    }
    #pragma unroll
    for (int it = 0; it < 6; ++it) {
        int flat = it * 64 + l;
        int row = flat / 24, seg = flat - row * 24;
        const unsigned short* e = (const unsigned short*)&vr[it];
        #pragma unroll
        for (int j = 0; j < 8; ++j)
            *(unsigned short*)(vt + (seg * 8 + j) * 64 + row * 2) = e[j];
    }

    const float scale = 0.07216878364870322f;  // 192^-0.5
    __hip_bfloat16* yp = qkv + (size_t)win * 16 * 576 + 384;

    #pragma unroll
    for (int h = 0; h < 6; ++h) {
        f32x4 s = {};
        s = __builtin_amdgcn_mfma_f32_16x16x32_bf16(kf[h], qf[h], s, 0, 0, 0);
        float sc[4];
        #pragma unroll
        for (int r = 0; r < 4; ++r) sc[r] = s[r] * scale;
        float mx = fmaxf(fmaxf(sc[0], sc[1]), fmaxf(sc[2], sc[3]));
        mx = fmaxf(mx, __shfl_xor(mx, 16));
        mx = fmaxf(mx, __shfl_xor(mx, 32));
        float e0 = __expf(sc[0] - mx), e1 = __expf(sc[1] - mx);
        float e2 = __expf(sc[2] - mx), e3 = __expf(sc[3] - mx);
        float sum = e0 + e1 + e2 + e3;
        sum += __shfl_xor(sum, 16);
        sum += __shfl_xor(sum, 32);
        float inv = 1.0f / sum;
        unsigned int pa = ((unsigned)f2bf(e1 * inv) << 16) | f2bf(e0 * inv);
        unsigned int pc = ((unsigned)f2bf(e3 * inv) << 16) | f2bf(e2 * inv);
        char* pw = pb + (l & 15) * 80 + (l >> 4) * 8;
        *(unsigned int*)pw = pa;
        *(unsigned int*)(pw + 4) = pc;
        bf16x8 pf = *(const bf16x8*)(pb + (l & 15) * 80 + (l >> 4) * 16);
        bf16x8 v0 = *(const bf16x8*)(vt + (h * 32 + (l & 15)) * 64 + (l >> 4) * 16);
        bf16x8 v1 = *(const bf16x8*)(vt + (h * 32 + 16 + (l & 15)) * 64 + (l >> 4) * 16);
        f32x4 y0 = {}, y1 = {};
        y0 = __builtin_amdgcn_mfma_f32_16x16x32_bf16(pf, v0, y0, 0, 0, 0);
        y1 = __builtin_amdgcn_mfma_f32_16x16x32_bf16(pf, v1, y1, 0, 0, 0);
        #pragma unroll
        for (int r = 0; r < 4; ++r) {
            int row = (l >> 4) * 4 + r;
            yp[(size_t)row * 576 + h * 32 + (l & 15)]      = __float2bfloat16(y0[r]);
            yp[(size_t)row * 576 + h * 32 + 16 + (l & 15)] = __float2bfloat16(y1[r]);
        }
    }
}

// ---------------- transpose out: x2[u,c] bf16 -> out[b,c,h,w] fp32 ----------
__global__ __launch_bounds__(256) void k_tout(const __hip_bfloat16* __restrict__ X2,
                                              float* __restrict__ out) {
    __shared__ float lds[CH * 65];
    int bh = blockIdx.x;
    int b = bh >> 6, h = bh & 63;
    int tid = threadIdx.x;
    int m1 = h >> 4, h0 = h & 15;
    int ubase = (b << 12) | (h0 << 8) | (m1 << 2);
    #pragma unroll
    for (int it = 0; it < 12; ++it) {
        int idx = it * 256 + tid;
        int tok = idx / 48, cq = idx - tok * 48;
        int u = ubase | ((tok & 15) << 4) | (tok >> 4);
        uint2 ma = *reinterpret_cast<const uint2*>(X2 + (size_t)u * CH + cq * 4);
        const unsigned short* ms = reinterpret_cast<const unsigned short*>(&ma);
        #pragma unroll
        for (int j = 0; j < 4; ++j) lds[(cq * 4 + j) * 65 + tok] = bf2f(ms[j]);
    }
    __syncthreads();
    float* op = out + (size_t)b * CH * 4096 + (size_t)h * 64;
    #pragma unroll
    for (int it = 0; it < 48; ++it) {
        int idx = it * 256 + tid;
        int c = idx >> 6;
        int w = idx & 63;
        op[(size_t)c * 4096 + w] = lds[c * 65 + w];
    }
}

// ---------------------------------------------------------------------------
extern "C" void kernel_launch(void* const* d_in, const int* in_sizes, int n_in,
                              void* d_out, int out_size, void* d_ws, size_t ws_size,
                              hipStream_t stream) {
    const float* x   = (const float*)d_in[0];
    const float* wq  = (const float*)d_in[1];
    const float* wk  = (const float*)d_in[2];
    const float* wv  = (const float*)d_in[3];
    const float* wo  = (const float*)d_in[4];
    const float* w1  = (const float*)d_in[5];
    const float* b1  = (const float*)d_in[6];
    const float* w2  = (const float*)d_in[7];
    const float* b2  = (const float*)d_in[8];
    const float* g1  = (const float*)d_in[9];
    const float* be1 = (const float*)d_in[10];
    const float* g2  = (const float*)d_in[11];
    const float* be2 = (const float*)d_in[12];
    float* out = (float*)d_out;

    char* ws = (char*)d_ws;
    const size_t SZ = (size_t)NTOK * CH * sizeof(__hip_bfloat16);  // 50,331,648 B
    __hip_bfloat16* xt   = (__hip_bfloat16*)(ws);             // xt -> x1 -> x2
    __hip_bfloat16* qkv  = (__hip_bfloat16*)(ws + SZ);        // [N,576]; later h
    __hip_bfloat16* x1   = xt;
    __hip_bfloat16* hb   = qkv;                               // [65536,768] chunk

    __hip_bfloat16* wqkvt = (__hip_bfloat16*)(ws + 4 * SZ);   // [576][192]
    __hip_bfloat16* wot   = wqkvt + 576 * 192;                // [192][192]
    __hip_bfloat16* w1t   = wot + 192 * 192;                  // [768][192]
    __hip_bfloat16* w2t   = w1t + 192 * 768;                  // [192][768]

    k_wprep<<<144, 256, 0, stream>>>(wq, wqkvt,             192, 192);
    k_wprep<<<144, 256, 0, stream>>>(wk, wqkvt + 192 * 192, 192, 192);
    k_wprep<<<144, 256, 0, stream>>>(wv, wqkvt + 384 * 192, 192, 192);
    k_wprep<<<144, 256, 0, stream>>>(wo, wot, 192, 192);
    k_wprep<<<576, 256, 0, stream>>>(w1, w1t, 192, 768);
    k_wprep<<<576, 256, 0, stream>>>(w2, w2t, 768, 192);

    k_tin<<<2048, 256, 0, stream>>>(x, xt);

    // qkv = xt @ [wq|wk|wv]: cols 0..511 in 128-wide tiles, 512..575 in 64-wide
    k_mgemm2<192, false, false><<<dim3(4, NTOK / 128), 256, 0, stream>>>(
        xt, wqkvt, nullptr, qkv, 0, 192, 576);
    k_mgemm<192, false, false><<<dim3(1, NTOK / 128), 256, 0, stream>>>(
        xt, wqkvt, nullptr, qkv, 512, 192, 576);
    // attention (y -> v-slots of qkv)
    k_attn2<<<NTOK / 64, 256, 0, stream>>>(qkv);
    // x1 = LN(y @ wo + xt)  (in-place over xt)
    k_gemmln<192, false><<<NTOK / 64, 256, 0, stream>>>(
        qkv + 384, wot, nullptr, xt, g1, be1, x1, 576);

    // MLP in 2 chunks of 65536 rows; x2 = LN(h @ w2 + b2 + x1) in-place
    const int CHUNK = 65536;
    for (int c = 0; c < 2; ++c) {
        __hip_bfloat16* x1c = x1 + (size_t)c * CHUNK * CH;
        k_mgemm2<192, true, true><<<dim3(6, CHUNK / 128), 256, 0, stream>>>(
            x1c, w1t, b1, hb, 0, 192, MLPD);
        k_gemmln<768, true><<<CHUNK / 64, 256, 0, stream>>>(
            hb, w2t, b2, x1c, g2, be2, x1c, MLPD);
    }
    k_tout<<<2048, 256, 0, stream>>>(x1, out);
}

// Round 13
// 446.515 us; speedup vs baseline: 1.1871x; 1.1871x over previous
//
#include <hip/hip_runtime.h>
#include <hip/hip_bf16.h>
#include <math.h>

// ---------------------------------------------------------------------------
// Round 13: r8 structure (441us, stable) with k_mgemm at BK=32:
// LDS dbuf 48KB -> 24KB => 6 blocks/CU (vs 3). Same stage-before-compute
// skeleton, same K-accumulation order (bit-identical numerics). r12's
// 128x128 tile (2 blocks/CU, 22% occ) regressed and is removed: these
// small-K GEMMs are latency-bound -- occupancy first.
//   k_wprep x6:  weights fp32 [K][N] -> bf16 transposed [N][K]
//   k_tin:       x[B,C,H,W] -> xt[u,192] bf16 (window-major token order)
//   k_mgemm:     qkv[u,576] = xt @ [wq|wk|wv]
//   k_attn2:     MFMA window attention; y overwrites v-slots of qkv
//   k_gemmln:    x1 = LN(y @ wo + xt)*g1+b1   (in-place over xt)
//   2x { k_mgemm w1+GELU ; k_gemmln w2+LN2 }  (x2 in-place over x1)
//   k_tout:      out = transpose(x2) fp32
// ---------------------------------------------------------------------------

#define DEVI __device__ __forceinline__

static constexpr int CH   = 192;
static constexpr int NTOK = 32 * 64 * 64;   // 131072
static constexpr int MLPD = 768;

typedef short bf16x8 __attribute__((ext_vector_type(8)));
typedef float f32x4  __attribute__((ext_vector_type(4)));

DEVI float bf2f(unsigned short u) { return __uint_as_float(((unsigned)u) << 16); }
DEVI unsigned short f2bf(float f) {
    __hip_bfloat16 h = __float2bfloat16(f);
    return *reinterpret_cast<unsigned short*>(&h);
}

DEVI void gload_lds16(const void* g, void* l) {
    __builtin_amdgcn_global_load_lds(
        (const __attribute__((address_space(1))) void*)g,
        (__attribute__((address_space(3))) void*)l, 16, 0, 0);
}

// ---------------- weight prep: W[K][N] fp32 -> Wt[N][K] bf16 ----------------
__global__ __launch_bounds__(256) void k_wprep(const float* __restrict__ W,
                                               __hip_bfloat16* __restrict__ Wt,
                                               int K, int N) {
    int idx = blockIdx.x * 256 + threadIdx.x;
    if (idx >= K * N) return;
    int n = idx / K, k = idx - n * K;
    Wt[idx] = __float2bfloat16(W[(size_t)k * N + n]);
}

// ---------------- transpose in: x[b,c,h,w] -> xt[u,c] bf16 ------------------
__global__ __launch_bounds__(256) void k_tin(const float* __restrict__ x,
                                             __hip_bfloat16* __restrict__ xt) {
    __shared__ float lds[CH * 65];
    int bh = blockIdx.x;              // b*64 + h
    int b = bh >> 6, h = bh & 63;
    const float* xp = x + ((size_t)b * CH) * 4096 + (size_t)h * 64;
    int tid = threadIdx.x;
    int w = tid & 63;
    #pragma unroll
    for (int it = 0; it < CH / 4; ++it) {
        int c = it * 4 + (tid >> 6);
        lds[c * 65 + w] = xp[(size_t)c * 4096 + w];
    }
    __syncthreads();
    int m1 = h >> 4, h0 = h & 15;
    int ubase = (b << 12) | (h0 << 8) | (m1 << 2);
    #pragma unroll
    for (int it = 0; it < 48; ++it) {
        int idx = it * 256 + tid;
        int tok = idx / CH;
        int c = idx - tok * CH;
        int u = ubase | ((tok & 15) << 4) | (tok >> 4);
        xt[(size_t)u * CH + c] = __float2bfloat16(lds[c * 65 + tok]);
    }
}

// ---------------- MFMA GEMM, 128x64 tile, BK=32, dbuf prefetch --------------
// C[r, n0..n0+63] = act(A[rows,K] @ Bt[N,K]^T + bias), n0 = nbase + bx*64.
// LDS rows are 64B (BK=32); swizzle: seg ^= (row>>1)&3 spreads 16 fragment
// lanes over 8 bank-groups (2-way = free). 24KB LDS => 6 blocks/CU.
template<int K, bool GELU, bool BIAS>
__global__ __launch_bounds__(256) void k_mgemm(const __hip_bfloat16* __restrict__ A,
                                               const __hip_bfloat16* __restrict__ Bt,
                                               const float* __restrict__ bias,
                                               __hip_bfloat16* __restrict__ Cm,
                                               const int nbase,
                                               const int LDA, const int LDC) {
    __shared__ __align__(16) char smem[24576];   // 2 x (As 8KB [128x32] + Bs 4KB [64x32])
    const int tid = threadIdx.x;
    const int l  = tid & 63;
    const int w  = tid >> 6;
    const int wr = w >> 1, wc = w & 1;
    const int r0 = blockIdx.y * 128;
    const int n0 = nbase + blockIdx.x * 64;
    constexpr int NT = K / 32;

    f32x4 acc[4][2] = {};

    auto stage = [&](int bi, int kt) {
        #pragma unroll
        for (int it = 0; it < 2; ++it) {          // A: 8 x 1KB chunks (128 rows x 64B)
            int c = it * 4 + w, s = c * 64 + l;
            int row = s >> 2, seg = s & 3;
            int sseg = seg ^ ((row >> 1) & 3);
            gload_lds16(A + (size_t)(r0 + row) * LDA + kt * 32 + sseg * 8,
                        smem + bi * 12288 + c * 1024);
        }
        {                                          // B: 4 x 1KB chunks (64 rows x 64B)
            int c = w, s = c * 64 + l;
            int row = s >> 2, seg = s & 3;
            int sseg = seg ^ ((row >> 1) & 3);
            gload_lds16(Bt + (size_t)(n0 + row) * K + kt * 32 + sseg * 8,
                        smem + bi * 12288 + 8192 + c * 1024);
        }
    };

    stage(0, 0);
    __syncthreads();
    #pragma unroll
    for (int kt = 0; kt < NT; ++kt) {
        const int cur = kt & 1;
        if (kt + 1 < NT) stage(cur ^ 1, kt + 1);   // prefetch BEFORE compute
        char* As = smem + cur * 12288;
        char* Bs = smem + cur * 12288 + 8192;
        const int kq = l >> 4;
        bf16x8 af[4], bfr[2];
        #pragma unroll
        for (int m = 0; m < 4; ++m) {
            int row = wr * 64 + m * 16 + (l & 15);
            af[m] = *(const bf16x8*)(As + row * 64 + ((kq ^ ((row >> 1) & 3)) << 4));
        }
        #pragma unroll
        for (int n = 0; n < 2; ++n) {
            int row = wc * 32 + n * 16 + (l & 15);
            bfr[n] = *(const bf16x8*)(Bs + row * 64 + ((kq ^ ((row >> 1) & 3)) << 4));
        }
        #pragma unroll
        for (int m = 0; m < 4; ++m)
            #pragma unroll
            for (int n = 0; n < 2; ++n)
                acc[m][n] = __builtin_amdgcn_mfma_f32_16x16x32_bf16(
                    af[m], bfr[n], acc[m][n], 0, 0, 0);
        __syncthreads();   // drains prefetch loads -> next buffer ready
    }

    const int rl = (l >> 4) * 4;
    const int cl = l & 15;
    #pragma unroll
    for (int n = 0; n < 2; ++n) {
        int col = n0 + wc * 32 + n * 16 + cl;
        float bv = 0.f;
        if constexpr (BIAS) bv = bias[col];
        #pragma unroll
        for (int m = 0; m < 4; ++m) {
            #pragma unroll
            for (int j = 0; j < 4; ++j) {
                size_t row = (size_t)r0 + wr * 64 + m * 16 + rl + j;
                float v = acc[m][n][j] + bv;
                if constexpr (GELU) v = 0.5f * v * (1.0f + erff(v * 0.70710678118654752f));
                Cm[row * LDC + col] = __float2bfloat16(v);
            }
        }
    }
}

// ---------------- full-row GEMM + residual + LayerNorm, dbuf prefetch -------
// Out[r,0..191] = LN(A[rows,K] @ Bt[192,K]^T + bias + Res[r,:]) * g + be.
template<int K, bool BIAS>
__global__ __launch_bounds__(256) void k_gemmln(const __hip_bfloat16* __restrict__ A,
                                                const __hip_bfloat16* __restrict__ Bt,
                                                const float* __restrict__ bias,
                                                const __hip_bfloat16* Res,
                                                const float* __restrict__ g,
                                                const float* __restrict__ be,
                                                __hip_bfloat16* Out,
                                                const int LDA) {
    __shared__ __align__(16) char smem[65536];   // 2 x (As 8KB + Bs 24KB)
    const int tid = threadIdx.x;
    const int l  = tid & 63;
    const int w  = tid >> 6;
    const int cl = l & 15;
    const int kq = l >> 4;
    const int r0 = blockIdx.x * 64;
    constexpr int NT = K / 64;

    f32x4 acc[12] = {};

    auto stage = [&](int bi, int kt) {
        #pragma unroll
        for (int it = 0; it < 2; ++it) {
            int c = it * 4 + w, s = c * 64 + l, row = s >> 3;
            int eb = ((s & 7) << 4) ^ ((row & 7) << 4);
            gload_lds16(A + (size_t)(r0 + row) * LDA + kt * 64 + (eb >> 1),
                        smem + bi * 32768 + c * 1024);
        }
        #pragma unroll
        for (int it = 0; it < 6; ++it) {
            int c = it * 4 + w, s = c * 64 + l, row = s >> 3;
            int eb = ((s & 7) << 4) ^ ((row & 7) << 4);
            gload_lds16(Bt + (size_t)row * K + kt * 64 + (eb >> 1),
                        smem + bi * 32768 + 8192 + c * 1024);
        }
    };

    stage(0, 0);
    __syncthreads();
    #pragma unroll
    for (int kt = 0; kt < NT; ++kt) {
        const int cur = kt & 1;
        if (kt + 1 < NT) stage(cur ^ 1, kt + 1);
        char* As = smem + cur * 32768;
        char* Bs = smem + cur * 32768 + 8192;
        #pragma unroll
        for (int ks = 0; ks < 2; ++ks) {
            int kb = ks * 64 + (kq << 4);
            int arow = w * 16 + cl;
            bf16x8 af = *(const bf16x8*)(As + arow * 128 + (kb ^ ((arow & 7) << 4)));
            #pragma unroll
            for (int n = 0; n < 12; ++n) {
                int row = n * 16 + cl;
                bf16x8 b = *(const bf16x8*)(Bs + row * 128 + (kb ^ ((row & 7) << 4)));
                acc[n] = __builtin_amdgcn_mfma_f32_16x16x32_bf16(af, b, acc[n], 0, 0, 0);
            }
        }
        __syncthreads();
    }

    float gv[12], bev[12], bv[12];
    #pragma unroll
    for (int n = 0; n < 12; ++n) {
        int col = n * 16 + cl;
        gv[n]  = g[col];
        bev[n] = be[col];
        bv[n]  = BIAS ? bias[col] : 0.f;
    }
    #pragma unroll
    for (int r = 0; r < 4; ++r) {
        size_t row = (size_t)r0 + w * 16 + kq * 4 + r;
        float v[12];
        float sum = 0.f;
        #pragma unroll
        for (int n = 0; n < 12; ++n) {
            int col = n * 16 + cl;
            v[n] = acc[n][r] + bv[n] +
                   bf2f(*reinterpret_cast<const unsigned short*>(Res + row * 192 + col));
            sum += v[n];
        }
        sum += __shfl_xor(sum, 1);
        sum += __shfl_xor(sum, 2);
        sum += __shfl_xor(sum, 4);
        sum += __shfl_xor(sum, 8);
        float mean = sum * (1.0f / 192.0f);
        float ss = 0.f;
        #pragma unroll
        for (int n = 0; n < 12; ++n) { v[n] -= mean; ss += v[n] * v[n]; }
        ss += __shfl_xor(ss, 1);
        ss += __shfl_xor(ss, 2);
        ss += __shfl_xor(ss, 4);
        ss += __shfl_xor(ss, 8);
        float rs = rsqrtf(ss * (1.0f / 192.0f) + 1e-5f);
        #pragma unroll
        for (int n = 0; n < 12; ++n) {
            int col = n * 16 + cl;
            *reinterpret_cast<unsigned short*>(Out + row * 192 + col) =
                f2bf(v[n] * rs * gv[n] + bev[n]);
        }
    }
}

// ---------------- MFMA window attention (r8-proven) -------------------------
__global__ __launch_bounds__(256) void k_attn2(__hip_bfloat16* qkv) {
    __shared__ __align__(16) char lds[4 * 13568];
    const int tid = threadIdx.x;
    const int l = tid & 63;
    const int w = tid >> 6;
    const int win = blockIdx.x * 4 + w;
    char* vt = lds + w * 13568;
    char* pb = vt + 12288;

    #pragma unroll
    for (int rr = 0; rr < 3; ++rr) {
        char* zp = vt + (l * 3 + rr) * 64 + 32;
        *(uint4*)zp        = make_uint4(0u, 0u, 0u, 0u);
        *(uint4*)(zp + 16) = make_uint4(0u, 0u, 0u, 0u);
    }
    {
        int r = l >> 2, o = (l & 3) * 8;
        *(uint2*)(pb + r * 80 + 32 + o) = make_uint2(0u, 0u);
    }

    const __hip_bfloat16* base = qkv + (size_t)win * 16 * 576;

    uint4 vr[6];
    #pragma unroll
    for (int it = 0; it < 6; ++it) {
        int flat = it * 64 + l;
        int row = flat / 24, seg = flat - row * 24;
        vr[it] = *(const uint4*)(base + (size_t)row * 576 + 384 + seg * 8);
    }
    bf16x8 qf[6], kf[6];
    #pragma unroll
    for (int h = 0; h < 6; ++h) {
        const __hip_bfloat16* rp = base + (size_t)(l & 15) * 576;
        int off = h * 32 + (l >> 4) * 8;
        qf[h] = *(const bf16x8*)(rp + off);
        kf[h] = *(const bf16x8*)(rp + 192 + off);
    }
    #pragma unroll
    for (int it = 0; it < 6; ++it) {
        int flat = it * 64 + l;
        int row = flat / 24, seg = flat - row * 24;
        const unsigned short* e = (const unsigned short*)&vr[it];
        #pragma unroll
        for (int j = 0; j < 8; ++j)
            *(unsigned short*)(vt + (seg * 8 + j) * 64 + row * 2) = e[j];
    }

    const float scale = 0.07216878364870322f;  // 192^-0.5
    __hip_bfloat16* yp = qkv + (size_t)win * 16 * 576 + 384;

    #pragma unroll
    for (int h = 0; h < 6; ++h) {
        f32x4 s = {};
        s = __builtin_amdgcn_mfma_f32_16x16x32_bf16(kf[h], qf[h], s, 0, 0, 0);
        float sc[4];
        #pragma unroll
        for (int r = 0; r < 4; ++r) sc[r] = s[r] * scale;
        float mx = fmaxf(fmaxf(sc[0], sc[1]), fmaxf(sc[2], sc[3]));
        mx = fmaxf(mx, __shfl_xor(mx, 16));
        mx = fmaxf(mx, __shfl_xor(mx, 32));
        float e0 = __expf(sc[0] - mx), e1 = __expf(sc[1] - mx);
        float e2 = __expf(sc[2] - mx), e3 = __expf(sc[3] - mx);
        float sum = e0 + e1 + e2 + e3;
        sum += __shfl_xor(sum, 16);
        sum += __shfl_xor(sum, 32);
        float inv = 1.0f / sum;
        unsigned int pa = ((unsigned)f2bf(e1 * inv) << 16) | f2bf(e0 * inv);
        unsigned int pc = ((unsigned)f2bf(e3 * inv) << 16) | f2bf(e2 * inv);
        char* pw = pb + (l & 15) * 80 + (l >> 4) * 8;
        *(unsigned int*)pw = pa;
        *(unsigned int*)(pw + 4) = pc;
        bf16x8 pf = *(const bf16x8*)(pb + (l & 15) * 80 + (l >> 4) * 16);
        bf16x8 v0 = *(const bf16x8*)(vt + (h * 32 + (l & 15)) * 64 + (l >> 4) * 16);
        bf16x8 v1 = *(const bf16x8*)(vt + (h * 32 + 16 + (l & 15)) * 64 + (l >> 4) * 16);
        f32x4 y0 = {}, y1 = {};
        y0 = __builtin_amdgcn_mfma_f32_16x16x32_bf16(pf, v0, y0, 0, 0, 0);
        y1 = __builtin_amdgcn_mfma_f32_16x16x32_bf16(pf, v1, y1, 0, 0, 0);
        #pragma unroll
        for (int r = 0; r < 4; ++r) {
            int row = (l >> 4) * 4 + r;
            yp[(size_t)row * 576 + h * 32 + (l & 15)]      = __float2bfloat16(y0[r]);
            yp[(size_t)row * 576 + h * 32 + 16 + (l & 15)] = __float2bfloat16(y1[r]);
        }
    }
}

// ---------------- transpose out: x2[u,c] bf16 -> out[b,c,h,w] fp32 ----------
__global__ __launch_bounds__(256) void k_tout(const __hip_bfloat16* __restrict__ X2,
                                              float* __restrict__ out) {
    __shared__ float lds[CH * 65];
    int bh = blockIdx.x;
    int b = bh >> 6, h = bh & 63;
    int tid = threadIdx.x;
    int m1 = h >> 4, h0 = h & 15;
    int ubase = (b << 12) | (h0 << 8) | (m1 << 2);
    #pragma unroll
    for (int it = 0; it < 12; ++it) {
        int idx = it * 256 + tid;
        int tok = idx / 48, cq = idx - tok * 48;
        int u = ubase | ((tok & 15) << 4) | (tok >> 4);
        uint2 ma = *reinterpret_cast<const uint2*>(X2 + (size_t)u * CH + cq * 4);
        const unsigned short* ms = reinterpret_cast<const unsigned short*>(&ma);
        #pragma unroll
        for (int j = 0; j < 4; ++j) lds[(cq * 4 + j) * 65 + tok] = bf2f(ms[j]);
    }
    __syncthreads();
    float* op = out + (size_t)b * CH * 4096 + (size_t)h * 64;
    #pragma unroll
    for (int it = 0; it < 48; ++it) {
        int idx = it * 256 + tid;
        int c = idx >> 6;
        int w = idx & 63;
        op[(size_t)c * 4096 + w] = lds[c * 65 + w];
    }
}

// ---------------------------------------------------------------------------
extern "C" void kernel_launch(void* const* d_in, const int* in_sizes, int n_in,
                              void* d_out, int out_size, void* d_ws, size_t ws_size,
                              hipStream_t stream) {
    const float* x   = (const float*)d_in[0];
    const float* wq  = (const float*)d_in[1];
    const float* wk  = (const float*)d_in[2];
    const float* wv  = (const float*)d_in[3];
    const float* wo  = (const float*)d_in[4];
    const float* w1  = (const float*)d_in[5];
    const float* b1  = (const float*)d_in[6];
    const float* w2  = (const float*)d_in[7];
    const float* b2  = (const float*)d_in[8];
    const float* g1  = (const float*)d_in[9];
    const float* be1 = (const float*)d_in[10];
    const float* g2  = (const float*)d_in[11];
    const float* be2 = (const float*)d_in[12];
    float* out = (float*)d_out;

    char* ws = (char*)d_ws;
    const size_t SZ = (size_t)NTOK * CH * sizeof(__hip_bfloat16);  // 50,331,648 B
    __hip_bfloat16* xt   = (__hip_bfloat16*)(ws);             // xt -> x1 -> x2
    __hip_bfloat16* qkv  = (__hip_bfloat16*)(ws + SZ);        // [N,576]; later h
    __hip_bfloat16* x1   = xt;
    __hip_bfloat16* hb   = qkv;                               // [65536,768] chunk

    __hip_bfloat16* wqkvt = (__hip_bfloat16*)(ws + 4 * SZ);   // [576][192]
    __hip_bfloat16* wot   = wqkvt + 576 * 192;                // [192][192]
    __hip_bfloat16* w1t   = wot + 192 * 192;                  // [768][192]
    __hip_bfloat16* w2t   = w1t + 192 * 768;                  // [192][768]

    k_wprep<<<144, 256, 0, stream>>>(wq, wqkvt,             192, 192);
    k_wprep<<<144, 256, 0, stream>>>(wk, wqkvt + 192 * 192, 192, 192);
    k_wprep<<<144, 256, 0, stream>>>(wv, wqkvt + 384 * 192, 192, 192);
    k_wprep<<<144, 256, 0, stream>>>(wo, wot, 192, 192);
    k_wprep<<<576, 256, 0, stream>>>(w1, w1t, 192, 768);
    k_wprep<<<576, 256, 0, stream>>>(w2, w2t, 768, 192);

    k_tin<<<2048, 256, 0, stream>>>(x, xt);

    // qkv = xt @ [wq|wk|wv]
    k_mgemm<192, false, false><<<dim3(9, NTOK / 128), 256, 0, stream>>>(
        xt, wqkvt, nullptr, qkv, 0, 192, 576);
    // attention (y -> v-slots of qkv)
    k_attn2<<<NTOK / 64, 256, 0, stream>>>(qkv);
    // x1 = LN(y @ wo + xt)  (in-place over xt)
    k_gemmln<192, false><<<NTOK / 64, 256, 0, stream>>>(
        qkv + 384, wot, nullptr, xt, g1, be1, x1, 576);

    // MLP in 2 chunks of 65536 rows; x2 = LN(h @ w2 + b2 + x1) in-place
    const int CHUNK = 65536;
    for (int c = 0; c < 2; ++c) {
        __hip_bfloat16* x1c = x1 + (size_t)c * CHUNK * CH;
        k_mgemm<192, true, true><<<dim3(12, CHUNK / 128), 256, 0, stream>>>(
            x1c, w1t, b1, hb, 0, 192, MLPD);
        k_gemmln<768, true><<<CHUNK / 64, 256, 0, stream>>>(
            hb, w2t, b2, x1c, g2, be2, x1c, MLPD);
    }
    k_tout<<<2048, 256, 0, stream>>>(x1, out);
}

// Round 14
// 444.220 us; speedup vs baseline: 1.1932x; 1.0052x over previous
//
#include <hip/hip_runtime.h>
#include <hip/hip_bf16.h>
#include <math.h>

// ---------------------------------------------------------------------------
// Round 14: r13 + operand-swapped MFMA in k_mgemm -> transposed C fragment:
// lane holds row=cl and 4 CONSECUTIVE cols (kq*4+j) => packed 8B C-stores
// (was 32 scalar 2B stores: VALU-bound epilogue + write-amplification).
// Arithmetic is bit-identical (same products, same positional accumulation).
//   k_wprep x6:  weights fp32 [K][N] -> bf16 transposed [N][K]
//   k_tin:       x[B,C,H,W] -> xt[u,192] bf16 (window-major token order)
//   k_mgemm:     qkv[u,576] = xt @ [wq|wk|wv]
//   k_attn2:     MFMA window attention; y overwrites v-slots of qkv
//   k_gemmln:    x1 = LN(y @ wo + xt)*g1+b1   (in-place over xt)
//   2x { k_mgemm w1+GELU ; k_gemmln w2+LN2 }  (x2 in-place over x1)
//   k_tout:      out = transpose(x2) fp32
// ---------------------------------------------------------------------------

#define DEVI __device__ __forceinline__

static constexpr int CH   = 192;
static constexpr int NTOK = 32 * 64 * 64;   // 131072
static constexpr int MLPD = 768;

typedef short bf16x8 __attribute__((ext_vector_type(8)));
typedef float f32x4  __attribute__((ext_vector_type(4)));

DEVI float bf2f(unsigned short u) { return __uint_as_float(((unsigned)u) << 16); }
DEVI unsigned short f2bf(float f) {
    __hip_bfloat16 h = __float2bfloat16(f);
    return *reinterpret_cast<unsigned short*>(&h);
}

DEVI void gload_lds16(const void* g, void* l) {
    __builtin_amdgcn_global_load_lds(
        (const __attribute__((address_space(1))) void*)g,
        (__attribute__((address_space(3))) void*)l, 16, 0, 0);
}

// ---------------- weight prep: W[K][N] fp32 -> Wt[N][K] bf16 ----------------
__global__ __launch_bounds__(256) void k_wprep(const float* __restrict__ W,
                                               __hip_bfloat16* __restrict__ Wt,
                                               int K, int N) {
    int idx = blockIdx.x * 256 + threadIdx.x;
    if (idx >= K * N) return;
    int n = idx / K, k = idx - n * K;
    Wt[idx] = __float2bfloat16(W[(size_t)k * N + n]);
}

// ---------------- transpose in: x[b,c,h,w] -> xt[u,c] bf16 ------------------
__global__ __launch_bounds__(256) void k_tin(const float* __restrict__ x,
                                             __hip_bfloat16* __restrict__ xt) {
    __shared__ float lds[CH * 65];
    int bh = blockIdx.x;              // b*64 + h
    int b = bh >> 6, h = bh & 63;
    const float* xp = x + ((size_t)b * CH) * 4096 + (size_t)h * 64;
    int tid = threadIdx.x;
    int w = tid & 63;
    #pragma unroll
    for (int it = 0; it < CH / 4; ++it) {
        int c = it * 4 + (tid >> 6);
        lds[c * 65 + w] = xp[(size_t)c * 4096 + w];
    }
    __syncthreads();
    int m1 = h >> 4, h0 = h & 15;
    int ubase = (b << 12) | (h0 << 8) | (m1 << 2);
    #pragma unroll
    for (int it = 0; it < 48; ++it) {
        int idx = it * 256 + tid;
        int tok = idx / CH;
        int c = idx - tok * CH;
        int u = ubase | ((tok & 15) << 4) | (tok >> 4);
        xt[(size_t)u * CH + c] = __float2bfloat16(lds[c * 65 + tok]);
    }
}

// ---------------- MFMA GEMM, 128x64 tile, BK=32, dbuf, swapped epilogue -----
// C[r, n0..n0+63] = act(A[rows,K] @ Bt[N,K]^T + bias), n0 = nbase + bx*64.
// mfma(B-frag, A-frag): lane owns output row (cl) x 4 consecutive cols
// (kq*4+j) -> packed 8B stores. Bit-identical accumulation to r13.
template<int K, bool GELU, bool BIAS>
__global__ __launch_bounds__(256) void k_mgemm(const __hip_bfloat16* __restrict__ A,
                                               const __hip_bfloat16* __restrict__ Bt,
                                               const float* __restrict__ bias,
                                               __hip_bfloat16* __restrict__ Cm,
                                               const int nbase,
                                               const int LDA, const int LDC) {
    __shared__ __align__(16) char smem[24576];   // 2 x (As 8KB [128x32] + Bs 4KB [64x32])
    const int tid = threadIdx.x;
    const int l  = tid & 63;
    const int w  = tid >> 6;
    const int wr = w >> 1, wc = w & 1;
    const int r0 = blockIdx.y * 128;
    const int n0 = nbase + blockIdx.x * 64;
    constexpr int NT = K / 32;

    f32x4 acc[4][2] = {};

    auto stage = [&](int bi, int kt) {
        #pragma unroll
        for (int it = 0; it < 2; ++it) {          // A: 8 x 1KB chunks (128 rows x 64B)
            int c = it * 4 + w, s = c * 64 + l;
            int row = s >> 2, seg = s & 3;
            int sseg = seg ^ ((row >> 1) & 3);
            gload_lds16(A + (size_t)(r0 + row) * LDA + kt * 32 + sseg * 8,
                        smem + bi * 12288 + c * 1024);
        }
        {                                          // B: 4 x 1KB chunks (64 rows x 64B)
            int c = w, s = c * 64 + l;
            int row = s >> 2, seg = s & 3;
            int sseg = seg ^ ((row >> 1) & 3);
            gload_lds16(Bt + (size_t)(n0 + row) * K + kt * 32 + sseg * 8,
                        smem + bi * 12288 + 8192 + c * 1024);
        }
    };

    stage(0, 0);
    __syncthreads();
    #pragma unroll
    for (int kt = 0; kt < NT; ++kt) {
        const int cur = kt & 1;
        if (kt + 1 < NT) stage(cur ^ 1, kt + 1);   // prefetch BEFORE compute
        char* As = smem + cur * 12288;
        char* Bs = smem + cur * 12288 + 8192;
        const int kq = l >> 4;
        bf16x8 af[4], bfr[2];
        #pragma unroll
        for (int m = 0; m < 4; ++m) {
            int row = wr * 64 + m * 16 + (l & 15);
            af[m] = *(const bf16x8*)(As + row * 64 + ((kq ^ ((row >> 1) & 3)) << 4));
        }
        #pragma unroll
        for (int n = 0; n < 2; ++n) {
            int row = wc * 32 + n * 16 + (l & 15);
            bfr[n] = *(const bf16x8*)(Bs + row * 64 + ((kq ^ ((row >> 1) & 3)) << 4));
        }
        #pragma unroll
        for (int m = 0; m < 4; ++m)
            #pragma unroll
            for (int n = 0; n < 2; ++n)
                acc[m][n] = __builtin_amdgcn_mfma_f32_16x16x32_bf16(
                    bfr[n], af[m], acc[m][n], 0, 0, 0);   // SWAPPED operands
        __syncthreads();   // drains prefetch loads -> next buffer ready
    }

    // epilogue: lane owns row = r0+wr*64+m*16+cl, cols n0+wc*32+n*16+kq*4+j
    const int cl = l & 15;
    const int kq = l >> 4;
    #pragma unroll
    for (int m = 0; m < 4; ++m) {
        size_t row = (size_t)r0 + wr * 64 + m * 16 + cl;
        #pragma unroll
        for (int n = 0; n < 2; ++n) {
            int colb = n0 + wc * 32 + n * 16 + kq * 4;
            float4 bv = make_float4(0.f, 0.f, 0.f, 0.f);
            if constexpr (BIAS) bv = *reinterpret_cast<const float4*>(bias + colb);
            union { uint2 u2; unsigned short us[4]; } pk;
            #pragma unroll
            for (int j = 0; j < 4; ++j) {
                float v = acc[m][n][j] + (&bv.x)[j];
                if constexpr (GELU) v = 0.5f * v * (1.0f + erff(v * 0.70710678118654752f));
                pk.us[j] = f2bf(v);
            }
            *reinterpret_cast<uint2*>(Cm + row * LDC + colb) = pk.u2;
        }
    }
}

// ---------------- full-row GEMM + residual + LayerNorm, dbuf prefetch -------
// Out[r,0..191] = LN(A[rows,K] @ Bt[192,K]^T + bias + Res[r,:]) * g + be.
template<int K, bool BIAS>
__global__ __launch_bounds__(256) void k_gemmln(const __hip_bfloat16* __restrict__ A,
                                                const __hip_bfloat16* __restrict__ Bt,
                                                const float* __restrict__ bias,
                                                const __hip_bfloat16* Res,
                                                const float* __restrict__ g,
                                                const float* __restrict__ be,
                                                __hip_bfloat16* Out,
                                                const int LDA) {
    __shared__ __align__(16) char smem[65536];   // 2 x (As 8KB + Bs 24KB)
    const int tid = threadIdx.x;
    const int l  = tid & 63;
    const int w  = tid >> 6;
    const int cl = l & 15;
    const int kq = l >> 4;
    const int r0 = blockIdx.x * 64;
    constexpr int NT = K / 64;

    f32x4 acc[12] = {};

    auto stage = [&](int bi, int kt) {
        #pragma unroll
        for (int it = 0; it < 2; ++it) {
            int c = it * 4 + w, s = c * 64 + l, row = s >> 3;
            int eb = ((s & 7) << 4) ^ ((row & 7) << 4);
            gload_lds16(A + (size_t)(r0 + row) * LDA + kt * 64 + (eb >> 1),
                        smem + bi * 32768 + c * 1024);
        }
        #pragma unroll
        for (int it = 0; it < 6; ++it) {
            int c = it * 4 + w, s = c * 64 + l, row = s >> 3;
            int eb = ((s & 7) << 4) ^ ((row & 7) << 4);
            gload_lds16(Bt + (size_t)row * K + kt * 64 + (eb >> 1),
                        smem + bi * 32768 + 8192 + c * 1024);
        }
    };

    stage(0, 0);
    __syncthreads();
    #pragma unroll
    for (int kt = 0; kt < NT; ++kt) {
        const int cur = kt & 1;
        if (kt + 1 < NT) stage(cur ^ 1, kt + 1);
        char* As = smem + cur * 32768;
        char* Bs = smem + cur * 32768 + 8192;
        #pragma unroll
        for (int ks = 0; ks < 2; ++ks) {
            int kb = ks * 64 + (kq << 4);
            int arow = w * 16 + cl;
            bf16x8 af = *(const bf16x8*)(As + arow * 128 + (kb ^ ((arow & 7) << 4)));
            #pragma unroll
            for (int n = 0; n < 12; ++n) {
                int row = n * 16 + cl;
                bf16x8 b = *(const bf16x8*)(Bs + row * 128 + (kb ^ ((row & 7) << 4)));
                acc[n] = __builtin_amdgcn_mfma_f32_16x16x32_bf16(af, b, acc[n], 0, 0, 0);
            }
        }
        __syncthreads();
    }

    float gv[12], bev[12], bv[12];
    #pragma unroll
    for (int n = 0; n < 12; ++n) {
        int col = n * 16 + cl;
        gv[n]  = g[col];
        bev[n] = be[col];
        bv[n]  = BIAS ? bias[col] : 0.f;
    }
    #pragma unroll
    for (int r = 0; r < 4; ++r) {
        size_t row = (size_t)r0 + w * 16 + kq * 4 + r;
        float v[12];
        float sum = 0.f;
        #pragma unroll
        for (int n = 0; n < 12; ++n) {
            int col = n * 16 + cl;
            v[n] = acc[n][r] + bv[n] +
                   bf2f(*reinterpret_cast<const unsigned short*>(Res + row * 192 + col));
            sum += v[n];
        }
        sum += __shfl_xor(sum, 1);
        sum += __shfl_xor(sum, 2);
        sum += __shfl_xor(sum, 4);
        sum += __shfl_xor(sum, 8);
        float mean = sum * (1.0f / 192.0f);
        float ss = 0.f;
        #pragma unroll
        for (int n = 0; n < 12; ++n) { v[n] -= mean; ss += v[n] * v[n]; }
        ss += __shfl_xor(ss, 1);
        ss += __shfl_xor(ss, 2);
        ss += __shfl_xor(ss, 4);
        ss += __shfl_xor(ss, 8);
        float rs = rsqrtf(ss * (1.0f / 192.0f) + 1e-5f);
        #pragma unroll
        for (int n = 0; n < 12; ++n) {
            int col = n * 16 + cl;
            *reinterpret_cast<unsigned short*>(Out + row * 192 + col) =
                f2bf(v[n] * rs * gv[n] + bev[n]);
        }
    }
}

// ---------------- MFMA window attention (r8-proven) -------------------------
__global__ __launch_bounds__(256) void k_attn2(__hip_bfloat16* qkv) {
    __shared__ __align__(16) char lds[4 * 13568];
    const int tid = threadIdx.x;
    const int l = tid & 63;
    const int w = tid >> 6;
    const int win = blockIdx.x * 4 + w;
    char* vt = lds + w * 13568;
    char* pb = vt + 12288;

    #pragma unroll
    for (int rr = 0; rr < 3; ++rr) {
        char* zp = vt + (l * 3 + rr) * 64 + 32;
        *(uint4*)zp        = make_uint4(0u, 0u, 0u, 0u);
        *(uint4*)(zp + 16) = make_uint4(0u, 0u, 0u, 0u);
    }
    {
        int r = l >> 2, o = (l & 3) * 8;
        *(uint2*)(pb + r * 80 + 32 + o) = make_uint2(0u, 0u);
    }

    const __hip_bfloat16* base = qkv + (size_t)win * 16 * 576;

    uint4 vr[6];
    #pragma unroll
    for (int it = 0; it < 6; ++it) {
        int flat = it * 64 + l;
        int row = flat / 24, seg = flat - row * 24;
        vr[it] = *(const uint4*)(base + (size_t)row * 576 + 384 + seg * 8);
    }
    bf16x8 qf[6], kf[6];
    #pragma unroll
    for (int h = 0; h < 6; ++h) {
        const __hip_bfloat16* rp = base + (size_t)(l & 15) * 576;
        int off = h * 32 + (l >> 4) * 8;
        qf[h] = *(const bf16x8*)(rp + off);
        kf[h] = *(const bf16x8*)(rp + 192 + off);
    }
    #pragma unroll
    for (int it = 0; it < 6; ++it) {
        int flat = it * 64 + l;
        int row = flat / 24, seg = flat - row * 24;
        const unsigned short* e = (const unsigned short*)&vr[it];
        #pragma unroll
        for (int j = 0; j < 8; ++j)
            *(unsigned short*)(vt + (seg * 8 + j) * 64 + row * 2) = e[j];
    }

    const float scale = 0.07216878364870322f;  // 192^-0.5
    __hip_bfloat16* yp = qkv + (size_t)win * 16 * 576 + 384;

    #pragma unroll
    for (int h = 0; h < 6; ++h) {
        f32x4 s = {};
        s = __builtin_amdgcn_mfma_f32_16x16x32_bf16(kf[h], qf[h], s, 0, 0, 0);
        float sc[4];
        #pragma unroll
        for (int r = 0; r < 4; ++r) sc[r] = s[r] * scale;
        float mx = fmaxf(fmaxf(sc[0], sc[1]), fmaxf(sc[2], sc[3]));
        mx = fmaxf(mx, __shfl_xor(mx, 16));
        mx = fmaxf(mx, __shfl_xor(mx, 32));
        float e0 = __expf(sc[0] - mx), e1 = __expf(sc[1] - mx);
        float e2 = __expf(sc[2] - mx), e3 = __expf(sc[3] - mx);
        float sum = e0 + e1 + e2 + e3;
        sum += __shfl_xor(sum, 16);
        sum += __shfl_xor(sum, 32);
        float inv = 1.0f / sum;
        unsigned int pa = ((unsigned)f2bf(e1 * inv) << 16) | f2bf(e0 * inv);
        unsigned int pc = ((unsigned)f2bf(e3 * inv) << 16) | f2bf(e2 * inv);
        char* pw = pb + (l & 15) * 80 + (l >> 4) * 8;
        *(unsigned int*)pw = pa;
        *(unsigned int*)(pw + 4) = pc;
        bf16x8 pf = *(const bf16x8*)(pb + (l & 15) * 80 + (l >> 4) * 16);
        bf16x8 v0 = *(const bf16x8*)(vt + (h * 32 + (l & 15)) * 64 + (l >> 4) * 16);
        bf16x8 v1 = *(const bf16x8*)(vt + (h * 32 + 16 + (l & 15)) * 64 + (l >> 4) * 16);
        f32x4 y0 = {}, y1 = {};
        y0 = __builtin_amdgcn_mfma_f32_16x16x32_bf16(pf, v0, y0, 0, 0, 0);
        y1 = __builtin_amdgcn_mfma_f32_16x16x32_bf16(pf, v1, y1, 0, 0, 0);
        #pragma unroll
        for (int r = 0; r < 4; ++r) {
            int row = (l >> 4) * 4 + r;
            yp[(size_t)row * 576 + h * 32 + (l & 15)]      = __float2bfloat16(y0[r]);
            yp[(size_t)row * 576 + h * 32 + 16 + (l & 15)] = __float2bfloat16(y1[r]);
        }
    }
}

// ---------------- transpose out: x2[u,c] bf16 -> out[b,c,h,w] fp32 ----------
__global__ __launch_bounds__(256) void k_tout(const __hip_bfloat16* __restrict__ X2,
                                              float* __restrict__ out) {
    __shared__ float lds[CH * 65];
    int bh = blockIdx.x;
    int b = bh >> 6, h = bh & 63;
    int tid = threadIdx.x;
    int m1 = h >> 4, h0 = h & 15;
    int ubase = (b << 12) | (h0 << 8) | (m1 << 2);
    #pragma unroll
    for (int it = 0; it < 12; ++it) {
        int idx = it * 256 + tid;
        int tok = idx / 48, cq = idx - tok * 48;
        int u = ubase | ((tok & 15) << 4) | (tok >> 4);
        uint2 ma = *reinterpret_cast<const uint2*>(X2 + (size_t)u * CH + cq * 4);
        const unsigned short* ms = reinterpret_cast<const unsigned short*>(&ma);
        #pragma unroll
        for (int j = 0; j < 4; ++j) lds[(cq * 4 + j) * 65 + tok] = bf2f(ms[j]);
    }
    __syncthreads();
    float* op = out + (size_t)b * CH * 4096 + (size_t)h * 64;
    #pragma unroll
    for (int it = 0; it < 48; ++it) {
        int idx = it * 256 + tid;
        int c = idx >> 6;
        int w = idx & 63;
        op[(size_t)c * 4096 + w] = lds[c * 65 + w];
    }
}

// ---------------------------------------------------------------------------
extern "C" void kernel_launch(void* const* d_in, const int* in_sizes, int n_in,
                              void* d_out, int out_size, void* d_ws, size_t ws_size,
                              hipStream_t stream) {
    const float* x   = (const float*)d_in[0];
    const float* wq  = (const float*)d_in[1];
    const float* wk  = (const float*)d_in[2];
    const float* wv  = (const float*)d_in[3];
    const float* wo  = (const float*)d_in[4];
    const float* w1  = (const float*)d_in[5];
    const float* b1  = (const float*)d_in[6];
    const float* w2  = (const float*)d_in[7];
    const float* b2  = (const float*)d_in[8];
    const float* g1  = (const float*)d_in[9];
    const float* be1 = (const float*)d_in[10];
    const float* g2  = (const float*)d_in[11];
    const float* be2 = (const float*)d_in[12];
    float* out = (float*)d_out;

    char* ws = (char*)d_ws;
    const size_t SZ = (size_t)NTOK * CH * sizeof(__hip_bfloat16);  // 50,331,648 B
    __hip_bfloat16* xt   = (__hip_bfloat16*)(ws);             // xt -> x1 -> x2
    __hip_bfloat16* qkv  = (__hip_bfloat16*)(ws + SZ);        // [N,576]; later h
    __hip_bfloat16* x1   = xt;
    __hip_bfloat16* hb   = qkv;                               // [65536,768] chunk

    __hip_bfloat16* wqkvt = (__hip_bfloat16*)(ws + 4 * SZ);   // [576][192]
    __hip_bfloat16* wot   = wqkvt + 576 * 192;                // [192][192]
    __hip_bfloat16* w1t   = wot + 192 * 192;                  // [768][192]
    __hip_bfloat16* w2t   = w1t + 192 * 768;                  // [192][768]

    k_wprep<<<144, 256, 0, stream>>>(wq, wqkvt,             192, 192);
    k_wprep<<<144, 256, 0, stream>>>(wk, wqkvt + 192 * 192, 192, 192);
    k_wprep<<<144, 256, 0, stream>>>(wv, wqkvt + 384 * 192, 192, 192);
    k_wprep<<<144, 256, 0, stream>>>(wo, wot, 192, 192);
    k_wprep<<<576, 256, 0, stream>>>(w1, w1t, 192, 768);
    k_wprep<<<576, 256, 0, stream>>>(w2, w2t, 768, 192);

    k_tin<<<2048, 256, 0, stream>>>(x, xt);

    // qkv = xt @ [wq|wk|wv]
    k_mgemm<192, false, false><<<dim3(9, NTOK / 128), 256, 0, stream>>>(
        xt, wqkvt, nullptr, qkv, 0, 192, 576);
    // attention (y -> v-slots of qkv)
    k_attn2<<<NTOK / 64, 256, 0, stream>>>(qkv);
    // x1 = LN(y @ wo + xt)  (in-place over xt)
    k_gemmln<192, false><<<NTOK / 64, 256, 0, stream>>>(
        qkv + 384, wot, nullptr, xt, g1, be1, x1, 576);

    // MLP in 2 chunks of 65536 rows; x2 = LN(h @ w2 + b2 + x1) in-place
    const int CHUNK = 65536;
    for (int c = 0; c < 2; ++c) {
        __hip_bfloat16* x1c = x1 + (size_t)c * CHUNK * CH;
        k_mgemm<192, true, true><<<dim3(12, CHUNK / 128), 256, 0, stream>>>(
            x1c, w1t, b1, hb, 0, 192, MLPD);
        k_gemmln<768, true><<<CHUNK / 64, 256, 0, stream>>>(
            hb, w2t, b2, x1c, g2, be2, x1c, MLPD);
    }
    k_tout<<<2048, 256, 0, stream>>>(x1, out);
}

// Round 15
// 405.712 us; speedup vs baseline: 1.3065x; 1.0949x over previous
//
#include <hip/hip_runtime.h>
#include <hip/hip_bf16.h>
#include <math.h>

// ---------------------------------------------------------------------------
// Round 15: r14 + XCD-aware block swizzle (T1) on k_mgemm.
// r14 counters: qkv/w1 FETCH=224MB vs ~51MB of inputs -- the NCB column-
// blocks sharing an A row-tile round-robin across the 8 XCD L2s. 1D grid +
// bijective swizzle swz=(bid&7)*per+(bid>>3) gives each XCD a contiguous
// work range (all cols of consecutive row-tiles) -> A re-reads become
// L2-local. Block->work remap only: bit-identical numerics.
//   k_wprep x6:  weights fp32 [K][N] -> bf16 transposed [N][K]
//   k_tin:       x[B,C,H,W] -> xt[u,192] bf16 (window-major token order)
//   k_mgemm:     qkv[u,576] = xt @ [wq|wk|wv]
//   k_attn2:     MFMA window attention; y overwrites v-slots of qkv
//   k_gemmln:    x1 = LN(y @ wo + xt)*g1+b1   (in-place over xt)
//   2x { k_mgemm w1+GELU ; k_gemmln w2+LN2 }  (x2 in-place over x1)
//   k_tout:      out = transpose(x2) fp32
// ---------------------------------------------------------------------------

#define DEVI __device__ __forceinline__

static constexpr int CH   = 192;
static constexpr int NTOK = 32 * 64 * 64;   // 131072
static constexpr int MLPD = 768;

typedef short bf16x8 __attribute__((ext_vector_type(8)));
typedef float f32x4  __attribute__((ext_vector_type(4)));

DEVI float bf2f(unsigned short u) { return __uint_as_float(((unsigned)u) << 16); }
DEVI unsigned short f2bf(float f) {
    __hip_bfloat16 h = __float2bfloat16(f);
    return *reinterpret_cast<unsigned short*>(&h);
}

DEVI void gload_lds16(const void* g, void* l) {
    __builtin_amdgcn_global_load_lds(
        (const __attribute__((address_space(1))) void*)g,
        (__attribute__((address_space(3))) void*)l, 16, 0, 0);
}

// ---------------- weight prep: W[K][N] fp32 -> Wt[N][K] bf16 ----------------
__global__ __launch_bounds__(256) void k_wprep(const float* __restrict__ W,
                                               __hip_bfloat16* __restrict__ Wt,
                                               int K, int N) {
    int idx = blockIdx.x * 256 + threadIdx.x;
    if (idx >= K * N) return;
    int n = idx / K, k = idx - n * K;
    Wt[idx] = __float2bfloat16(W[(size_t)k * N + n]);
}

// ---------------- transpose in: x[b,c,h,w] -> xt[u,c] bf16 ------------------
__global__ __launch_bounds__(256) void k_tin(const float* __restrict__ x,
                                             __hip_bfloat16* __restrict__ xt) {
    __shared__ float lds[CH * 65];
    int bh = blockIdx.x;              // b*64 + h
    int b = bh >> 6, h = bh & 63;
    const float* xp = x + ((size_t)b * CH) * 4096 + (size_t)h * 64;
    int tid = threadIdx.x;
    int w = tid & 63;
    #pragma unroll
    for (int it = 0; it < CH / 4; ++it) {
        int c = it * 4 + (tid >> 6);
        lds[c * 65 + w] = xp[(size_t)c * 4096 + w];
    }
    __syncthreads();
    int m1 = h >> 4, h0 = h & 15;
    int ubase = (b << 12) | (h0 << 8) | (m1 << 2);
    #pragma unroll
    for (int it = 0; it < 48; ++it) {
        int idx = it * 256 + tid;
        int tok = idx / CH;
        int c = idx - tok * CH;
        int u = ubase | ((tok & 15) << 4) | (tok >> 4);
        xt[(size_t)u * CH + c] = __float2bfloat16(lds[c * 65 + tok]);
    }
}

// ---------------- MFMA GEMM, 128x64 tile, BK=32, dbuf, swapped epilogue -----
// 1D grid (gridDim.x % 8 == 0), bijective XCD swizzle; work = row*NCB + col.
// C[r, n0..n0+63] = act(A[rows,K] @ Bt[N,K]^T + bias), n0 = nbase + col*64.
template<int K, int NCB, bool GELU, bool BIAS>
__global__ __launch_bounds__(256) void k_mgemm(const __hip_bfloat16* __restrict__ A,
                                               const __hip_bfloat16* __restrict__ Bt,
                                               const float* __restrict__ bias,
                                               __hip_bfloat16* __restrict__ Cm,
                                               const int nbase,
                                               const int LDA, const int LDC) {
    __shared__ __align__(16) char smem[24576];   // 2 x (As 8KB [128x32] + Bs 4KB [64x32])
    const int tid = threadIdx.x;
    const int l  = tid & 63;
    const int w  = tid >> 6;
    const int wr = w >> 1, wc = w & 1;
    // XCD-aware swizzle: workgroups round-robin XCDs by dispatch id, so
    // (bid&7) is the XCD; give each XCD a contiguous work chunk.
    const int per = (int)gridDim.x >> 3;
    const int bid = (int)blockIdx.x;
    const int swz = (bid & 7) * per + (bid >> 3);
    const int r0 = (swz / NCB) * 128;
    const int n0 = nbase + (swz % NCB) * 64;
    constexpr int NT = K / 32;

    f32x4 acc[4][2] = {};

    auto stage = [&](int bi, int kt) {
        #pragma unroll
        for (int it = 0; it < 2; ++it) {          // A: 8 x 1KB chunks (128 rows x 64B)
            int c = it * 4 + w, s = c * 64 + l;
            int row = s >> 2, seg = s & 3;
            int sseg = seg ^ ((row >> 1) & 3);
            gload_lds16(A + (size_t)(r0 + row) * LDA + kt * 32 + sseg * 8,
                        smem + bi * 12288 + c * 1024);
        }
        {                                          // B: 4 x 1KB chunks (64 rows x 64B)
            int c = w, s = c * 64 + l;
            int row = s >> 2, seg = s & 3;
            int sseg = seg ^ ((row >> 1) & 3);
            gload_lds16(Bt + (size_t)(n0 + row) * K + kt * 32 + sseg * 8,
                        smem + bi * 12288 + 8192 + c * 1024);
        }
    };

    stage(0, 0);
    __syncthreads();
    #pragma unroll
    for (int kt = 0; kt < NT; ++kt) {
        const int cur = kt & 1;
        if (kt + 1 < NT) stage(cur ^ 1, kt + 1);   // prefetch BEFORE compute
        char* As = smem + cur * 12288;
        char* Bs = smem + cur * 12288 + 8192;
        const int kq = l >> 4;
        bf16x8 af[4], bfr[2];
        #pragma unroll
        for (int m = 0; m < 4; ++m) {
            int row = wr * 64 + m * 16 + (l & 15);
            af[m] = *(const bf16x8*)(As + row * 64 + ((kq ^ ((row >> 1) & 3)) << 4));
        }
        #pragma unroll
        for (int n = 0; n < 2; ++n) {
            int row = wc * 32 + n * 16 + (l & 15);
            bfr[n] = *(const bf16x8*)(Bs + row * 64 + ((kq ^ ((row >> 1) & 3)) << 4));
        }
        #pragma unroll
        for (int m = 0; m < 4; ++m)
            #pragma unroll
            for (int n = 0; n < 2; ++n)
                acc[m][n] = __builtin_amdgcn_mfma_f32_16x16x32_bf16(
                    bfr[n], af[m], acc[m][n], 0, 0, 0);   // swapped operands
        __syncthreads();   // drains prefetch loads -> next buffer ready
    }

    // epilogue: lane owns row = r0+wr*64+m*16+cl, cols n0+wc*32+n*16+kq*4+j
    const int cl = l & 15;
    const int kq = l >> 4;
    #pragma unroll
    for (int m = 0; m < 4; ++m) {
        size_t row = (size_t)r0 + wr * 64 + m * 16 + cl;
        #pragma unroll
        for (int n = 0; n < 2; ++n) {
            int colb = n0 + wc * 32 + n * 16 + kq * 4;
            float4 bv = make_float4(0.f, 0.f, 0.f, 0.f);
            if constexpr (BIAS) bv = *reinterpret_cast<const float4*>(bias + colb);
            union { uint2 u2; unsigned short us[4]; } pk;
            #pragma unroll
            for (int j = 0; j < 4; ++j) {
                float v = acc[m][n][j] + (&bv.x)[j];
                if constexpr (GELU) v = 0.5f * v * (1.0f + erff(v * 0.70710678118654752f));
                pk.us[j] = f2bf(v);
            }
            *reinterpret_cast<uint2*>(Cm + row * LDC + colb) = pk.u2;
        }
    }
}

// ---------------- full-row GEMM + residual + LayerNorm, dbuf prefetch -------
// Out[r,0..191] = LN(A[rows,K] @ Bt[192,K]^T + bias + Res[r,:]) * g + be.
template<int K, bool BIAS>
__global__ __launch_bounds__(256) void k_gemmln(const __hip_bfloat16* __restrict__ A,
                                                const __hip_bfloat16* __restrict__ Bt,
                                                const float* __restrict__ bias,
                                                const __hip_bfloat16* Res,
                                                const float* __restrict__ g,
                                                const float* __restrict__ be,
                                                __hip_bfloat16* Out,
                                                const int LDA) {
    __shared__ __align__(16) char smem[65536];   // 2 x (As 8KB + Bs 24KB)
    const int tid = threadIdx.x;
    const int l  = tid & 63;
    const int w  = tid >> 6;
    const int cl = l & 15;
    const int kq = l >> 4;
    const int r0 = blockIdx.x * 64;
    constexpr int NT = K / 64;

    f32x4 acc[12] = {};

    auto stage = [&](int bi, int kt) {
        #pragma unroll
        for (int it = 0; it < 2; ++it) {
            int c = it * 4 + w, s = c * 64 + l, row = s >> 3;
            int eb = ((s & 7) << 4) ^ ((row & 7) << 4);
            gload_lds16(A + (size_t)(r0 + row) * LDA + kt * 64 + (eb >> 1),
                        smem + bi * 32768 + c * 1024);
        }
        #pragma unroll
        for (int it = 0; it < 6; ++it) {
            int c = it * 4 + w, s = c * 64 + l, row = s >> 3;
            int eb = ((s & 7) << 4) ^ ((row & 7) << 4);
            gload_lds16(Bt + (size_t)row * K + kt * 64 + (eb >> 1),
                        smem + bi * 32768 + 8192 + c * 1024);
        }
    };

    stage(0, 0);
    __syncthreads();
    #pragma unroll
    for (int kt = 0; kt < NT; ++kt) {
        const int cur = kt & 1;
        if (kt + 1 < NT) stage(cur ^ 1, kt + 1);
        char* As = smem + cur * 32768;
        char* Bs = smem + cur * 32768 + 8192;
        #pragma unroll
        for (int ks = 0; ks < 2; ++ks) {
            int kb = ks * 64 + (kq << 4);
            int arow = w * 16 + cl;
            bf16x8 af = *(const bf16x8*)(As + arow * 128 + (kb ^ ((arow & 7) << 4)));
            #pragma unroll
            for (int n = 0; n < 12; ++n) {
                int row = n * 16 + cl;
                bf16x8 b = *(const bf16x8*)(Bs + row * 128 + (kb ^ ((row & 7) << 4)));
                acc[n] = __builtin_amdgcn_mfma_f32_16x16x32_bf16(af, b, acc[n], 0, 0, 0);
            }
        }
        __syncthreads();
    }

    float gv[12], bev[12], bv[12];
    #pragma unroll
    for (int n = 0; n < 12; ++n) {
        int col = n * 16 + cl;
        gv[n]  = g[col];
        bev[n] = be[col];
        bv[n]  = BIAS ? bias[col] : 0.f;
    }
    #pragma unroll
    for (int r = 0; r < 4; ++r) {
        size_t row = (size_t)r0 + w * 16 + kq * 4 + r;
        float v[12];
        float sum = 0.f;
        #pragma unroll
        for (int n = 0; n < 12; ++n) {
            int col = n * 16 + cl;
            v[n] = acc[n][r] + bv[n] +
                   bf2f(*reinterpret_cast<const unsigned short*>(Res + row * 192 + col));
            sum += v[n];
        }
        sum += __shfl_xor(sum, 1);
        sum += __shfl_xor(sum, 2);
        sum += __shfl_xor(sum, 4);
        sum += __shfl_xor(sum, 8);
        float mean = sum * (1.0f / 192.0f);
        float ss = 0.f;
        #pragma unroll
        for (int n = 0; n < 12; ++n) { v[n] -= mean; ss += v[n] * v[n]; }
        ss += __shfl_xor(ss, 1);
        ss += __shfl_xor(ss, 2);
        ss += __shfl_xor(ss, 4);
        ss += __shfl_xor(ss, 8);
        float rs = rsqrtf(ss * (1.0f / 192.0f) + 1e-5f);
        #pragma unroll
        for (int n = 0; n < 12; ++n) {
            int col = n * 16 + cl;
            *reinterpret_cast<unsigned short*>(Out + row * 192 + col) =
                f2bf(v[n] * rs * gv[n] + bev[n]);
        }
    }
}

// ---------------- MFMA window attention (r8-proven) -------------------------
__global__ __launch_bounds__(256) void k_attn2(__hip_bfloat16* qkv) {
    __shared__ __align__(16) char lds[4 * 13568];
    const int tid = threadIdx.x;
    const int l = tid & 63;
    const int w = tid >> 6;
    const int win = blockIdx.x * 4 + w;
    char* vt = lds + w * 13568;
    char* pb = vt + 12288;

    #pragma unroll
    for (int rr = 0; rr < 3; ++rr) {
        char* zp = vt + (l * 3 + rr) * 64 + 32;
        *(uint4*)zp        = make_uint4(0u, 0u, 0u, 0u);
        *(uint4*)(zp + 16) = make_uint4(0u, 0u, 0u, 0u);
    }
    {
        int r = l >> 2, o = (l & 3) * 8;
        *(uint2*)(pb + r * 80 + 32 + o) = make_uint2(0u, 0u);
    }

    const __hip_bfloat16* base = qkv + (size_t)win * 16 * 576;

    uint4 vr[6];
    #pragma unroll
    for (int it = 0; it < 6; ++it) {
        int flat = it * 64 + l;
        int row = flat / 24, seg = flat - row * 24;
        vr[it] = *(const uint4*)(base + (size_t)row * 576 + 384 + seg * 8);
    }
    bf16x8 qf[6], kf[6];
    #pragma unroll
    for (int h = 0; h < 6; ++h) {
        const __hip_bfloat16* rp = base + (size_t)(l & 15) * 576;
        int off = h * 32 + (l >> 4) * 8;
        qf[h] = *(const bf16x8*)(rp + off);
        kf[h] = *(const bf16x8*)(rp + 192 + off);
    }
    #pragma unroll
    for (int it = 0; it < 6; ++it) {
        int flat = it * 64 + l;
        int row = flat / 24, seg = flat - row * 24;
        const unsigned short* e = (const unsigned short*)&vr[it];
        #pragma unroll
        for (int j = 0; j < 8; ++j)
            *(unsigned short*)(vt + (seg * 8 + j) * 64 + row * 2) = e[j];
    }

    const float scale = 0.07216878364870322f;  // 192^-0.5
    __hip_bfloat16* yp = qkv + (size_t)win * 16 * 576 + 384;

    #pragma unroll
    for (int h = 0; h < 6; ++h) {
        f32x4 s = {};
        s = __builtin_amdgcn_mfma_f32_16x16x32_bf16(kf[h], qf[h], s, 0, 0, 0);
        float sc[4];
        #pragma unroll
        for (int r = 0; r < 4; ++r) sc[r] = s[r] * scale;
        float mx = fmaxf(fmaxf(sc[0], sc[1]), fmaxf(sc[2], sc[3]));
        mx = fmaxf(mx, __shfl_xor(mx, 16));
        mx = fmaxf(mx, __shfl_xor(mx, 32));
        float e0 = __expf(sc[0] - mx), e1 = __expf(sc[1] - mx);
        float e2 = __expf(sc[2] - mx), e3 = __expf(sc[3] - mx);
        float sum = e0 + e1 + e2 + e3;
        sum += __shfl_xor(sum, 16);
        sum += __shfl_xor(sum, 32);
        float inv = 1.0f / sum;
        unsigned int pa = ((unsigned)f2bf(e1 * inv) << 16) | f2bf(e0 * inv);
        unsigned int pc = ((unsigned)f2bf(e3 * inv) << 16) | f2bf(e2 * inv);
        char* pw = pb + (l & 15) * 80 + (l >> 4) * 8;
        *(unsigned int*)pw = pa;
        *(unsigned int*)(pw + 4) = pc;
        bf16x8 pf = *(const bf16x8*)(pb + (l & 15) * 80 + (l >> 4) * 16);
        bf16x8 v0 = *(const bf16x8*)(vt + (h * 32 + (l & 15)) * 64 + (l >> 4) * 16);
        bf16x8 v1 = *(const bf16x8*)(vt + (h * 32 + 16 + (l & 15)) * 64 + (l >> 4) * 16);
        f32x4 y0 = {}, y1 = {};
        y0 = __builtin_amdgcn_mfma_f32_16x16x32_bf16(pf, v0, y0, 0, 0, 0);
        y1 = __builtin_amdgcn_mfma_f32_16x16x32_bf16(pf, v1, y1, 0, 0, 0);
        #pragma unroll
        for (int r = 0; r < 4; ++r) {
            int row = (l >> 4) * 4 + r;
            yp[(size_t)row * 576 + h * 32 + (l & 15)]      = __float2bfloat16(y0[r]);
            yp[(size_t)row * 576 + h * 32 + 16 + (l & 15)] = __float2bfloat16(y1[r]);
        }
    }
}

// ---------------- transpose out: x2[u,c] bf16 -> out[b,c,h,w] fp32 ----------
__global__ __launch_bounds__(256) void k_tout(const __hip_bfloat16* __restrict__ X2,
                                              float* __restrict__ out) {
    __shared__ float lds[CH * 65];
    int bh = blockIdx.x;
    int b = bh >> 6, h = bh & 63;
    int tid = threadIdx.x;
    int m1 = h >> 4, h0 = h & 15;
    int ubase = (b << 12) | (h0 << 8) | (m1 << 2);
    #pragma unroll
    for (int it = 0; it < 12; ++it) {
        int idx = it * 256 + tid;
        int tok = idx / 48, cq = idx - tok * 48;
        int u = ubase | ((tok & 15) << 4) | (tok >> 4);
        uint2 ma = *reinterpret_cast<const uint2*>(X2 + (size_t)u * CH + cq * 4);
        const unsigned short* ms = reinterpret_cast<const unsigned short*>(&ma);
        #pragma unroll
        for (int j = 0; j < 4; ++j) lds[(cq * 4 + j) * 65 + tok] = bf2f(ms[j]);
    }
    __syncthreads();
    float* op = out + (size_t)b * CH * 4096 + (size_t)h * 64;
    #pragma unroll
    for (int it = 0; it < 48; ++it) {
        int idx = it * 256 + tid;
        int c = idx >> 6;
        int w = idx & 63;
        op[(size_t)c * 4096 + w] = lds[c * 65 + w];
    }
}

// ---------------------------------------------------------------------------
extern "C" void kernel_launch(void* const* d_in, const int* in_sizes, int n_in,
                              void* d_out, int out_size, void* d_ws, size_t ws_size,
                              hipStream_t stream) {
    const float* x   = (const float*)d_in[0];
    const float* wq  = (const float*)d_in[1];
    const float* wk  = (const float*)d_in[2];
    const float* wv  = (const float*)d_in[3];
    const float* wo  = (const float*)d_in[4];
    const float* w1  = (const float*)d_in[5];
    const float* b1  = (const float*)d_in[6];
    const float* w2  = (const float*)d_in[7];
    const float* b2  = (const float*)d_in[8];
    const float* g1  = (const float*)d_in[9];
    const float* be1 = (const float*)d_in[10];
    const float* g2  = (const float*)d_in[11];
    const float* be2 = (const float*)d_in[12];
    float* out = (float*)d_out;

    char* ws = (char*)d_ws;
    const size_t SZ = (size_t)NTOK * CH * sizeof(__hip_bfloat16);  // 50,331,648 B
    __hip_bfloat16* xt   = (__hip_bfloat16*)(ws);             // xt -> x1 -> x2
    __hip_bfloat16* qkv  = (__hip_bfloat16*)(ws + SZ);        // [N,576]; later h
    __hip_bfloat16* x1   = xt;
    __hip_bfloat16* hb   = qkv;                               // [65536,768] chunk

    __hip_bfloat16* wqkvt = (__hip_bfloat16*)(ws + 4 * SZ);   // [576][192]
    __hip_bfloat16* wot   = wqkvt + 576 * 192;                // [192][192]
    __hip_bfloat16* w1t   = wot + 192 * 192;                  // [768][192]
    __hip_bfloat16* w2t   = w1t + 192 * 768;                  // [192][768]

    k_wprep<<<144, 256, 0, stream>>>(wq, wqkvt,             192, 192);
    k_wprep<<<144, 256, 0, stream>>>(wk, wqkvt + 192 * 192, 192, 192);
    k_wprep<<<144, 256, 0, stream>>>(wv, wqkvt + 384 * 192, 192, 192);
    k_wprep<<<144, 256, 0, stream>>>(wo, wot, 192, 192);
    k_wprep<<<576, 256, 0, stream>>>(w1, w1t, 192, 768);
    k_wprep<<<576, 256, 0, stream>>>(w2, w2t, 768, 192);

    k_tin<<<2048, 256, 0, stream>>>(x, xt);

    // qkv = xt @ [wq|wk|wv]: 1D grid 9*1024 = 9216 (%8==0), XCD-swizzled
    k_mgemm<192, 9, false, false><<<9216, 256, 0, stream>>>(
        xt, wqkvt, nullptr, qkv, 0, 192, 576);
    // attention (y -> v-slots of qkv)
    k_attn2<<<NTOK / 64, 256, 0, stream>>>(qkv);
    // x1 = LN(y @ wo + xt)  (in-place over xt)
    k_gemmln<192, false><<<NTOK / 64, 256, 0, stream>>>(
        qkv + 384, wot, nullptr, xt, g1, be1, x1, 576);

    // MLP in 2 chunks of 65536 rows; x2 = LN(h @ w2 + b2 + x1) in-place
    const int CHUNK = 65536;
    for (int c = 0; c < 2; ++c) {
        __hip_bfloat16* x1c = x1 + (size_t)c * CHUNK * CH;
        // w1: 1D grid 12*512 = 6144 (%8==0), XCD-swizzled
        k_mgemm<192, 12, true, true><<<6144, 256, 0, stream>>>(
            x1c, w1t, b1, hb, 0, 192, MLPD);
        k_gemmln<768, true><<<CHUNK / 64, 256, 0, stream>>>(
            hb, w2t, b2, x1c, g2, be2, x1c, MLPD);
    }
    k_tout<<<2048, 256, 0, stream>>>(x1, out);
}